// Round 13
// baseline (257.451 us; speedup 1.0000x reference)
//
#include <hip/hip_runtime.h>
#include <hip/hip_bf16.h>

#define H 16
#define BB 2
#define SS 2048
#define DMODEL 1024
#define ROWS (BB * SS)   // 4096

typedef __attribute__((ext_vector_type(8))) short bf16x8;
typedef __attribute__((ext_vector_type(4))) short short4v;
typedef __attribute__((ext_vector_type(4))) float f32x4;

__device__ __forceinline__ short f2bf(float f) {
    union { float f; unsigned u; } v; v.f = f;
    unsigned r = v.u + 0x7fffu + ((v.u >> 16) & 1u);
    return (short)(r >> 16);
}

__device__ __forceinline__ void gload_lds16(const void* g, void* l) {
    __builtin_amdgcn_global_load_lds(
        (const __attribute__((address_space(1))) char*)g,
        (__attribute__((address_space(3))) char*)l, 16, 0, 0);
}

// fp32 -> bf16: q,k (4M each) and 4 weight matrices (1M each).
__global__ __launch_bounds__(256)
void cvt(const float* __restrict__ q, const float* __restrict__ k,
         const float* __restrict__ wq, const float* __restrict__ wk,
         const float* __restrict__ wv, const float* __restrict__ wo,
         short* __restrict__ Qb, short* __restrict__ Kb, short* __restrict__ Wb)
{
    const int bid = blockIdx.x;
    const float* s; short* d; int lb;
    if (bid < 2048)      { s = q; d = Qb; lb = bid; }
    else if (bid < 4096) { s = k; d = Kb; lb = bid - 2048; }
    else {
        const int w = (bid - 4096) >> 9;
        lb = (bid - 4096) & 511;
        s = (w == 0) ? wq : (w == 1) ? wk : (w == 2) ? wv : wo;
        d = Wb + (size_t)w * (DMODEL * DMODEL);
    }
    const int p = lb * 256 + threadIdx.x;
    const f32x4* sv = (const f32x4*)s;
    f32x4 a = sv[2 * p], c = sv[2 * p + 1];
    bf16x8 o;
    o[0] = f2bf(a[0]); o[1] = f2bf(a[1]); o[2] = f2bf(a[2]); o[3] = f2bf(a[3]);
    o[4] = f2bf(c[0]); o[5] = f2bf(c[1]); o[6] = f2bf(c[2]); o[7] = f2bf(c[3]);
    ((bf16x8*)d)[p] = o;
}

// BK=32 stagers. LDS tile [R][32] shorts; physical chunk of row r, logical c:
// c ^ ((r>>1)&3)  -> conflict-free b128 frag reads. Swizzle on global source.
__device__ __forceinline__ void stage32_128(const short* __restrict__ src, int kt,
                                            char* lds, int wid, int lane)
{
#pragma unroll
    for (int i = 0; i < 2; i++) {
        const int blk = wid * 2 + i;
        const int row = blk * 16 + (lane >> 2);
        const int g   = (lane & 3) ^ ((lane >> 3) & 3);
        gload_lds16(&src[(size_t)row * DMODEL + kt + g * 8], lds + blk * 1024);
    }
}

__device__ __forceinline__ void stage32_64(const short* __restrict__ src, int kt,
                                           char* lds, int wid, int lane)
{
    const int row = wid * 16 + (lane >> 2);
    const int g   = (lane & 3) ^ ((lane >> 3) & 3);
    gload_lds16(&src[(size_t)row * DMODEL + kt + g * 8], lds + wid * 1024);
}

// Fused Q/K/V projection. 128x64 tiles, 1536 blocks = 6 blocks/CU (6 waves/SIMD).
// xcd = fbid&7 gets 64 tiles of EACH op; op0/1 tiles span a 512-row activation
// panel per XCD, op2 a 512-row v panel -> L2-resident. Drain-style dbuf.
__global__ __launch_bounds__(256, 6)
void qkv_proj(const short* __restrict__ Qb, const short* __restrict__ Kb,
              const float* __restrict__ vf,
              const short* __restrict__ Wq, const short* __restrict__ Wk,
              const short* __restrict__ Wv,
              const float* __restrict__ bq, const float* __restrict__ bk,
              const float* __restrict__ bv,
              short* __restrict__ Qh, short* __restrict__ Kh,
              short* __restrict__ Vt)
{
    __shared__ short As[2][128 * 32];
    __shared__ short Bs[2][64 * 32];

    const int fbid = blockIdx.x;
    const int xcd  = fbid & 7;
    const int slot = fbid >> 3;         // 0..191
    const int op   = slot % 3;
    const int idx  = slot / 3;          // 0..63
    const int t    = threadIdx.x;
    const int lane = t & 63;
    const int wid  = t >> 6;
    const int wm   = wid >> 1;          // 0..1  (64-row half)
    const int wn   = wid & 1;           // 0..1  (32-col half)
    const int l15  = lane & 15;
    const int l4   = lane >> 4;

    const short* Asrc; const short* Bsrc = nullptr; const float* bias;
    short* C; int m0, n0; float scale = 1.0f;
    if (op == 0) {
        Asrc = Qb; Bsrc = Wq; bias = bq; C = Qh;
        m0 = (xcd * 4 + (idx >> 4)) * 128; n0 = (idx & 15) * 64; scale = 0.125f;
    } else if (op == 1) {
        Asrc = Kb; Bsrc = Wk; bias = bk; C = Kh;
        m0 = (xcd * 4 + (idx >> 4)) * 128; n0 = (idx & 15) * 64;
    } else {
        Asrc = Wv; bias = bv; C = Vt;
        m0 = (idx & 7) * 128; n0 = (xcd * 8 + (idx >> 3)) * 64;
    }
    Asrc += (size_t)m0 * DMODEL;

    f32x4 acc[4][2];
#pragma unroll
    for (int i = 0; i < 4; i++)
#pragma unroll
        for (int j = 0; j < 2; j++) acc[i][j] = (f32x4)0.0f;

    const int ch = (l4 ^ ((l15 >> 1) & 3)) * 8;
    // op2 fp32 B staging geometry: thread t -> row t>>2 (0..63), 8 floats at (t&3)*8
    const int brow = t >> 2, bcol = (t & 3) * 8;

    auto writeBrowV = [&](int buf, const f32x4* br) {
        bf16x8 w;
        w[0]=f2bf(br[0][0]); w[1]=f2bf(br[0][1]); w[2]=f2bf(br[0][2]); w[3]=f2bf(br[0][3]);
        w[4]=f2bf(br[1][0]); w[5]=f2bf(br[1][1]); w[6]=f2bf(br[1][2]); w[7]=f2bf(br[1][3]);
        const int cp = (t & 3) ^ ((brow >> 1) & 3);
        *(bf16x8*)&Bs[buf][brow * 32 + cp * 8] = w;
    };

    // prologue: tile 0 into buffer 0
    stage32_128(Asrc, 0, (char*)As[0], wid, lane);
    if (op < 2) {
        stage32_64(Bsrc + (size_t)n0 * DMODEL, 0, (char*)Bs[0], wid, lane);
    } else {
        f32x4 br[2];
        const f32x4* p = (const f32x4*)&vf[(size_t)(n0 + brow) * DMODEL + bcol];
        br[0] = p[0]; br[1] = p[1];
        writeBrowV(0, br);
    }
    __syncthreads();

    int cur = 0;
    for (int kt = 0; kt < DMODEL; kt += 32) {
        const int nxt = cur ^ 1;
        const bool pre = (kt + 32 < DMODEL);
        f32x4 br[2];
        if (pre) {
            stage32_128(Asrc, kt + 32, (char*)As[nxt], wid, lane);
            if (op < 2) {
                stage32_64(Bsrc + (size_t)n0 * DMODEL, kt + 32, (char*)Bs[nxt], wid, lane);
            } else {
                const f32x4* p = (const f32x4*)&vf[(size_t)(n0 + brow) * DMODEL + kt + 32 + bcol];
                br[0] = p[0]; br[1] = p[1];
            }
        }

        bf16x8 a[4], b[2];
#pragma unroll
        for (int i = 0; i < 4; i++)
            a[i] = *(const bf16x8*)&As[cur][(wm * 64 + i * 16 + l15) * 32 + ch];
#pragma unroll
        for (int j = 0; j < 2; j++)
            b[j] = *(const bf16x8*)&Bs[cur][(wn * 32 + j * 16 + l15) * 32 + ch];
        __builtin_amdgcn_s_setprio(1);
#pragma unroll
        for (int i = 0; i < 4; i++)
#pragma unroll
            for (int j = 0; j < 2; j++)
                acc[i][j] = __builtin_amdgcn_mfma_f32_16x16x32_bf16(a[i], b[j], acc[i][j], 0, 0, 0);
        __builtin_amdgcn_s_setprio(0);

        if (pre && op == 2) writeBrowV(nxt, br);
        __syncthreads();
        cur = nxt;
    }

#pragma unroll
    for (int i = 0; i < 4; i++) {
        const int mbase = m0 + wm * 64 + i * 16 + l4 * 4;
#pragma unroll
        for (int j = 0; j < 2; j++) {
            const int n = n0 + wn * 32 + j * 16 + l15;
#pragma unroll
            for (int r = 0; r < 4; r++) {
                const int m = mbase + r;
                if (op < 2) {
                    float y = (acc[i][j][r] + bias[n]) * scale;
                    const int b_ = m >> 11, s_ = m & 2047;
                    const int h_ = n >> 6,  d_ = n & 63;
                    C[((((size_t)b_ * H + h_) * SS + s_) << 6) + d_] = f2bf(y);
                } else {
                    C[(size_t)m * ROWS + n] = f2bf(acc[i][j][r] + bias[m]);
                }
            }
        }
    }
}

// O-projection: OW[4096][1024] fp32 = Oc @ Wo^T + bo. 64x128 tiles, BK=32,
// counted-vmcnt 2-ahead triple-buffer, 512 blocks XCD-chunked.
__global__ __launch_bounds__(256, 3)
void oproj(const short* __restrict__ Oc, const short* __restrict__ Wo,
           const float* __restrict__ bo, float* __restrict__ out)
{
    __shared__ short As[3][64 * 32];
    __shared__ short Bs[3][128 * 32];

    const int fbid = blockIdx.x;
    const int vbid = (fbid & 7) * 64 + (fbid >> 3);
    const int m0   = (vbid >> 3) * 64;
    const int n0   = (vbid & 7) * 128;
    const int t    = threadIdx.x;
    const int lane = t & 63;
    const int wid  = t >> 6;
    const int wm   = wid >> 1;
    const int wn   = wid & 1;
    const int l15  = lane & 15;
    const int l4   = lane >> 4;
    const int ch   = (l4 ^ ((l15 >> 1) & 3)) * 8;

    f32x4 acc[2][4];
#pragma unroll
    for (int i = 0; i < 2; i++)
#pragma unroll
        for (int j = 0; j < 4; j++) acc[i][j] = (f32x4)0.0f;

    const short* Ap = Oc + (size_t)m0 * DMODEL;
    const short* Bp = Wo + (size_t)n0 * DMODEL;

    stage32_64 (Ap, 0,  (char*)As[0], wid, lane);
    stage32_128(Bp, 0,  (char*)Bs[0], wid, lane);
    stage32_64 (Ap, 32, (char*)As[1], wid, lane);
    stage32_128(Bp, 32, (char*)Bs[1], wid, lane);

    for (int it = 0; it < 32; ++it) {
        if (it < 31) asm volatile("s_waitcnt vmcnt(3)" ::: "memory");
        else         asm volatile("s_waitcnt vmcnt(0)" ::: "memory");
        __builtin_amdgcn_s_barrier();
        __builtin_amdgcn_sched_barrier(0);
        if (it + 2 < 32) {
            const int nb = (it + 2) % 3;
            stage32_64 (Ap, (it + 2) * 32, (char*)As[nb], wid, lane);
            stage32_128(Bp, (it + 2) * 32, (char*)Bs[nb], wid, lane);
        }
        const short* Ab = As[it % 3];
        const short* Bb = Bs[it % 3];
        bf16x8 a[2], b[4];
#pragma unroll
        for (int i = 0; i < 2; i++)
            a[i] = *(const bf16x8*)&Ab[(wm * 32 + i * 16 + l15) * 32 + ch];
#pragma unroll
        for (int j = 0; j < 4; j++)
            b[j] = *(const bf16x8*)&Bb[(wn * 64 + j * 16 + l15) * 32 + ch];
        __builtin_amdgcn_s_setprio(1);
#pragma unroll
        for (int i = 0; i < 2; i++)
#pragma unroll
            for (int j = 0; j < 4; j++)
                acc[i][j] = __builtin_amdgcn_mfma_f32_16x16x32_bf16(a[i], b[j], acc[i][j], 0, 0, 0);
        __builtin_amdgcn_s_setprio(0);
    }

#pragma unroll
    for (int i = 0; i < 2; i++) {
        const int mbase = m0 + wm * 32 + i * 16 + l4 * 4;
#pragma unroll
        for (int j = 0; j < 4; j++) {
            const int n = n0 + wn * 64 + j * 16 + l15;
#pragma unroll
            for (int r = 0; r < 4; r++)
                out[(size_t)(mbase + r) * DMODEL + n] = acc[i][j][r] + bo[n];
        }
    }
}

// Flash attention, causal, paired q-tiles, double-buffered K/V, 1 barrier/iter.
// SWAPPED QK^T: S^T = mfma(K,Q) -> each lane owns one q-row (q=l15), 16 kv regs.
__global__ __launch_bounds__(256, 2)
void attn_fwd(const short* __restrict__ Qh, const short* __restrict__ Kh,
              const short* __restrict__ Vt, short* __restrict__ Oc)
{
    __shared__ short Ks[2][64][64];
    __shared__ short Vs[2][64][64];
    __shared__ short Ps[4][16][72];   // [wave][q_local][kv]

    const int t    = threadIdx.x;
    const int lane = t & 63;
    const int wid  = t >> 6;
    const int fbid = blockIdx.x;
    const int vbid = (fbid & 7) * 64 + (fbid >> 3);
    const int bh   = vbid >> 4;
    const int qp   = vbid & 15;
    const int b    = bh >> 4;
    const int h    = bh & 15;
    const int l15  = lane & 15;
    const int l4   = lane >> 4;

    const int srow = wid * 8 + (lane >> 3);
    const int sch  = lane & 7;
    const int ldsoff = wid * 1024;

    auto stage = [&](int buf, int kvt) {
#pragma unroll
        for (int i = 0; i < 2; i++) {
            const int row = i * 32 + srow;
            const int chg = sch ^ (row & 7);
            gload_lds16(&Kh[((size_t)bh * SS + kvt * 64 + row) * 64 + chg * 8],
                        (char*)Ks + buf * 8192 + ldsoff + i * 4096);
            gload_lds16(&Vt[((size_t)(h * 64 + row)) * ROWS + b * SS + kvt * 64 + chg * 8],
                        (char*)Vs + buf * 8192 + ldsoff + i * 4096);
        }
    };

    for (int half = 0; half < 2; ++half) {
        const int qt = half ? (31 - qp) : qp;

        bf16x8 qa[2];
        {
            const int qrow = qt * 64 + wid * 16 + l15;
            const size_t base = ((size_t)bh * SS + qrow) * 64;
            qa[0] = *(const bf16x8*)&Qh[base + l4 * 8];
            qa[1] = *(const bf16x8*)&Qh[base + 32 + l4 * 8];
        }

        f32x4 accO[4];
#pragma unroll
        for (int i = 0; i < 4; i++) accO[i] = (f32x4)0.f;
        float mrun = -1e30f, lrun = 0.f;

        stage(0, 0);
        __syncthreads();

        int cur = 0;
        for (int kvt = 0; kvt <= qt; ++kvt) {
            if (kvt < qt) stage(cur ^ 1, kvt + 1);

            f32x4 sc[4];
#pragma unroll
            for (int i = 0; i < 4; i++) sc[i] = (f32x4)0.f;
            __builtin_amdgcn_s_setprio(1);
#pragma unroll
            for (int kk = 0; kk < 2; kk++) {
#pragma unroll
                for (int fn = 0; fn < 4; fn++) {
                    const int chk = (kk * 4 + l4) ^ (l15 & 7);
                    bf16x8 kb = *(const bf16x8*)&Ks[cur][fn * 16 + l15][chk * 8];
                    sc[fn] = __builtin_amdgcn_mfma_f32_16x16x32_bf16(kb, qa[kk], sc[fn], 0, 0, 0);
                }
            }
            __builtin_amdgcn_s_setprio(0);

            if (kvt == qt) {
                const int qg = wid * 16 + l15;
#pragma unroll
                for (int fn = 0; fn < 4; fn++)
#pragma unroll
                    for (int r = 0; r < 4; r++)
                        if (fn * 16 + l4 * 4 + r > qg) sc[fn][r] = -1e30f;
            }

            float pmax = sc[0][0];
#pragma unroll
            for (int fn = 0; fn < 4; fn++)
#pragma unroll
                for (int r = 0; r < 4; r++)
                    pmax = fmaxf(pmax, sc[fn][r]);
            pmax = fmaxf(pmax, __shfl_xor(pmax, 16));
            pmax = fmaxf(pmax, __shfl_xor(pmax, 32));

            if (__any(pmax > mrun + 8.0f)) {
                const float mn = fmaxf(mrun, pmax);
                const float es = __expf(mrun - mn);
                mrun = mn;
                lrun *= es;
                float esr[4];
#pragma unroll
                for (int r = 0; r < 4; r++) esr[r] = __shfl(es, l4 * 4 + r);
#pragma unroll
                for (int fd = 0; fd < 4; fd++)
#pragma unroll
                    for (int r = 0; r < 4; r++) accO[fd][r] *= esr[r];
            }

            float rs = 0.f;
#pragma unroll
            for (int fn = 0; fn < 4; fn++)
#pragma unroll
                for (int r = 0; r < 4; r++) {
                    const float p = __expf(sc[fn][r] - mrun);
                    sc[fn][r] = p;
                    rs += p;
                }
            rs += __shfl_xor(rs, 16);
            rs += __shfl_xor(rs, 32);
            lrun += rs;

#pragma unroll
            for (int fn = 0; fn < 4; fn++) {
                short4v w4;
                w4[0] = f2bf(sc[fn][0]); w4[1] = f2bf(sc[fn][1]);
                w4[2] = f2bf(sc[fn][2]); w4[3] = f2bf(sc[fn][3]);
                *(short4v*)&Ps[wid][l15][fn * 16 + l4 * 4] = w4;
            }

            __builtin_amdgcn_s_setprio(1);
#pragma unroll
            for (int kk = 0; kk < 2; kk++) {
                bf16x8 pa = *(const bf16x8*)&Ps[wid][l15][kk * 32 + l4 * 8];
#pragma unroll
                for (int fd = 0; fd < 4; fd++) {
                    const int chk = (kk * 4 + l4) ^ (l15 & 7);
                    bf16x8 vb = *(const bf16x8*)&Vs[cur][fd * 16 + l15][chk * 8];
                    accO[fd] = __builtin_amdgcn_mfma_f32_16x16x32_bf16(pa, vb, accO[fd], 0, 0, 0);
                }
            }
            __builtin_amdgcn_s_setprio(0);

            __syncthreads();
            cur ^= 1;
        }

        float linv[4];
#pragma unroll
        for (int r = 0; r < 4; r++) linv[r] = 1.0f / __shfl(lrun, l4 * 4 + r);
#pragma unroll
        for (int fd = 0; fd < 4; fd++)
#pragma unroll
            for (int r = 0; r < 4; r++) {
                const int q = qt * 64 + wid * 16 + l4 * 4 + r;
                const size_t idx = ((size_t)b * SS + q) * DMODEL + h * 64 + fd * 16 + l15;
                Oc[idx] = f2bf(accO[fd][r] * linv[r]);
            }
    }
}

extern "C" void kernel_launch(void* const* d_in, const int* in_sizes, int n_in,
                              void* d_out, int out_size, void* d_ws, size_t ws_size,
                              hipStream_t stream) {
    const float* q   = (const float*)d_in[0];
    const float* k   = (const float*)d_in[1];
    const float* v   = (const float*)d_in[2];
    const float* w_q = (const float*)d_in[4];
    const float* b_q = (const float*)d_in[5];
    const float* w_k = (const float*)d_in[6];
    const float* b_k = (const float*)d_in[7];
    const float* w_v = (const float*)d_in[8];
    const float* b_v = (const float*)d_in[9];
    const float* w_o = (const float*)d_in[10];
    const float* b_o = (const float*)d_in[11];

    const size_t T = (size_t)ROWS * DMODEL;   // 4M elements
    const size_t W = (size_t)DMODEL * DMODEL; // 1M elements
    short* Qh  = (short*)d_ws;
    short* Kh  = Qh + T;
    short* Vt  = Kh + T;
    short* Wb  = Vt + T;
    short* Wq16 = Wb, *Wk16 = Wb + W, *Wv16 = Wb + 2 * W, *Wo16 = Wb + 3 * W;
    short* Qb  = (short*)d_out;
    short* Kb  = Qb + T;
    short* Oc  = (short*)d_out;
    float* OW  = (float*)d_ws;                // oproj fp32 result (over dead Qh/Kh)

    dim3 blk(256);
    cvt<<<dim3(6144), blk, 0, stream>>>(q, k, w_q, w_k, w_v, w_o, Qb, Kb, Wb);
    qkv_proj<<<dim3(1536), blk, 0, stream>>>(Qb, Kb, v, Wq16, Wk16, Wv16,
                                             b_q, b_k, b_v, Qh, Kh, Vt);
    attn_fwd<<<dim3(512), blk, 0, stream>>>(Qh, Kh, Vt, Oc);
    oproj<<<dim3(512), blk, 0, stream>>>(Oc, Wo16, b_o, OW);
    hipMemcpyAsync(d_out, d_ws, (size_t)ROWS * DMODEL * sizeof(float),
                   hipMemcpyDeviceToDevice, stream);
}